// Round 3
// baseline (13482.106 us; speedup 1.0000x reference)
//
#include <hip/hip_runtime.h>

#define DGRID 128
#define E1 127
#define E2 125
#define E3 123
#define C1P 12            // x1 channels padded 9 -> 12 (48 B, 16B-aligned)

// ---------------- stage 0: zero dense grid ----------------
__global__ __launch_bounds__(256) void zero_k(float4* __restrict__ p, int n4) {
    int i = blockIdx.x * 256 + threadIdx.x;
    if (i < n4) p[i] = make_float4(0.f, 0.f, 0.f, 0.f);
}

// ---------------- stage 1: scatter voxels into dense grid ----------------
__global__ __launch_bounds__(256) void scatter_k(const int* __restrict__ coords,
                                                 const float* __restrict__ voxels,
                                                 float* __restrict__ dense, int N) {
    int i = blockIdx.x * blockDim.x + threadIdx.x;
    if (i >= N * 3) return;
    int n = i / 3, c = i - n * 3;
    int b = coords[n * 4 + 0];
    int z = coords[n * 4 + 1];
    int y = coords[n * 4 + 2];
    int x = coords[n * 4 + 3];
    int idx = (((b * DGRID + z) * DGRID + y) * DGRID + x) * 3 + c;
    atomicAdd(&dense[idx], voxels[n * 3 + c]);
}

// ---------------- stage 2: fused conv1+conv2  dense -> x2 [B,125,125,125,5] ----------------
// Block: 256 threads, output tile 8x8x8 (2 z-outputs per thread).
// x1 tile 10x10x10 computed in LDS (channel-padded to 12), conv1 reads dense from global (L1/L2).
__global__ __launch_bounds__(256) void conv12_k(const float* __restrict__ dense,
                                                const float* __restrict__ W1,
                                                const float* __restrict__ W2,
                                                float* __restrict__ x2) {
    __shared__ float sW1[216];
    __shared__ float sW2[1215];
    __shared__ __align__(16) float sX1[1000 * C1P];   // 48000 B

    const int tid = threadIdx.x;
    for (int i = tid; i < 216; i += 256) sW1[i] = W1[i];
    for (int i = tid; i < 1215; i += 256) sW2[i] = W2[i];

    int blk = blockIdx.x;
    const int txt = blk & 15; blk >>= 4;
    const int tyt = blk & 15; blk >>= 4;
    const int tzt = blk & 15; blk >>= 4;
    const int b = blk;
    const int z0 = tzt * 8, y0 = tyt * 8, x0 = txt * 8;

    __syncthreads();   // weights visible (cheap; also orders LDS reuse across grid replays)

    // ---- phase 1: compute x1 tile [10][10][10] in LDS from global dense
    for (int p = tid; p < 1000; p += 256) {
        const int xx = p % 10;
        const int xy = (p / 10) % 10;
        const int xz = p / 100;
        const int gz = z0 + xz, gy = y0 + xy, gx = x0 + xx;
        float acc[9];
#pragma unroll
        for (int o = 0; o < 9; ++o) acc[o] = 0.f;
#pragma unroll
        for (int kz = 0; kz < 2; ++kz) {
            const int dz = min(gz + kz, DGRID - 1);
#pragma unroll
            for (int ky = 0; ky < 2; ++ky) {
                const int dy = min(gy + ky, DGRID - 1);
#pragma unroll
                for (int kx = 0; kx < 2; ++kx) {
                    const int dx = min(gx + kx, DGRID - 1);
                    const float* dp = dense + (((b * DGRID + dz) * DGRID + dy) * DGRID + dx) * 3;
                    const float* wp = sW1 + ((kz * 2 + ky) * 2 + kx) * 27;
#pragma unroll
                    for (int ci = 0; ci < 3; ++ci) {
                        const float v = dp[ci];
#pragma unroll
                        for (int o = 0; o < 9; ++o) acc[o] += v * wp[ci * 9 + o];
                    }
                }
            }
        }
        float* op = sX1 + p * C1P;
#pragma unroll
        for (int o = 0; o < 9; ++o) op[o] = acc[o];
        // channels 9..11 left unwritten: read via b128 below but never multiplied
    }
    __syncthreads();

    // ---- phase 2: conv2 from LDS, 2 z-outputs per thread
    const int lx = tid & 7;
    const int ly = (tid >> 3) & 7;
    const int lz = tid >> 6;            // 0..3
    const int oy = y0 + ly, ox = x0 + lx;
    const int oz0 = z0 + 2 * lz;

    float acc0[5], acc1[5];
#pragma unroll
    for (int o = 0; o < 5; ++o) { acc0[o] = 0.f; acc1[o] = 0.f; }

#pragma unroll
    for (int r = 0; r < 4; ++r) {       // x1 z-row = 2*lz + r
        const float* rowp = sX1 + ((2 * lz + r) * 100) * C1P;
#pragma unroll
        for (int ky = 0; ky < 3; ++ky) {
#pragma unroll
            for (int kx = 0; kx < 3; ++kx) {
                const float* p = rowp + ((ly + ky) * 10 + (lx + kx)) * C1P;
                const float4 a = *(const float4*)p;
                const float4 c = *(const float4*)(p + 4);
                const float4 e = *(const float4*)(p + 8);
                const float vin[9] = {a.x, a.y, a.z, a.w, c.x, c.y, c.z, c.w, e.x};
                if (r < 3) {
                    const float* wp = sW2 + ((r * 3 + ky) * 3 + kx) * 45;
#pragma unroll
                    for (int ci = 0; ci < 9; ++ci)
#pragma unroll
                        for (int o = 0; o < 5; ++o) acc0[o] += vin[ci] * wp[ci * 5 + o];
                }
                if (r > 0) {
                    const float* wp = sW2 + (((r - 1) * 3 + ky) * 3 + kx) * 45;
#pragma unroll
                    for (int ci = 0; ci < 9; ++ci)
#pragma unroll
                        for (int o = 0; o < 5; ++o) acc1[o] += vin[ci] * wp[ci * 5 + o];
                }
            }
        }
    }

    if (oy < E2 && ox < E2) {
        if (oz0 < E2) {
            float* op = x2 + (((b * E2 + oz0) * E2 + oy) * E2 + ox) * 5;
#pragma unroll
            for (int o = 0; o < 5; ++o) op[o] = acc0[o];
        }
        if (oz0 + 1 < E2) {
            float* op = x2 + (((b * E2 + oz0 + 1) * E2 + oy) * E2 + ox) * 5;
#pragma unroll
            for (int o = 0; o < 5; ++o) op[o] = acc1[o];
        }
    }
}

// ---------------- stage 3: conv3 + bias + relu  [B,125,125,125,5] -> [B,123,123,123,3] ----------------
// Block: 256 threads, output tile 8x8x8 (2 z-outputs per thread), reads x2 from global.
__global__ __launch_bounds__(256) void conv3_k(const float* __restrict__ x2,
                                               const float* __restrict__ W3,
                                               const float* __restrict__ b3,
                                               float* __restrict__ out) {
    __shared__ float w[405];
    for (int i = threadIdx.x; i < 405; i += 256) w[i] = W3[i];
    __syncthreads();

    int blk = blockIdx.x;
    const int txt = blk & 15; blk >>= 4;
    const int tyt = blk & 15; blk >>= 4;
    const int tzt = blk & 15; blk >>= 4;
    const int b = blk;
    const int z0 = tzt * 8, y0 = tyt * 8, x0 = txt * 8;

    const int tid = threadIdx.x;
    const int lx = tid & 7;
    const int ly = (tid >> 3) & 7;
    const int lz = tid >> 6;            // 0..3
    const int oy = y0 + ly, ox = x0 + lx;
    const int oz0 = z0 + 2 * lz;

    const float bb0 = b3[0], bb1 = b3[1], bb2 = b3[2];
    float acc0[3] = {bb0, bb1, bb2};
    float acc1[3] = {bb0, bb1, bb2};

#pragma unroll
    for (int r = 0; r < 4; ++r) {       // x2 z-row = oz0 + r
        const int iz = min(oz0 + r, E2 - 1);
#pragma unroll
        for (int ky = 0; ky < 3; ++ky) {
            const int iy = min(oy + ky, E2 - 1);
#pragma unroll
            for (int kx = 0; kx < 3; ++kx) {
                const int ix = min(ox + kx, E2 - 1);
                const float* p = x2 + (((b * E2 + iz) * E2 + iy) * E2 + ix) * 5;
                float v[5];
#pragma unroll
                for (int ci = 0; ci < 5; ++ci) v[ci] = p[ci];
                if (r < 3) {
                    const float* wp = w + ((r * 3 + ky) * 3 + kx) * 15;
#pragma unroll
                    for (int ci = 0; ci < 5; ++ci)
#pragma unroll
                        for (int o = 0; o < 3; ++o) acc0[o] += v[ci] * wp[ci * 3 + o];
                }
                if (r > 0) {
                    const float* wp = w + (((r - 1) * 3 + ky) * 3 + kx) * 15;
#pragma unroll
                    for (int ci = 0; ci < 5; ++ci)
#pragma unroll
                        for (int o = 0; o < 3; ++o) acc1[o] += v[ci] * wp[ci * 3 + o];
                }
            }
        }
    }

    if (oy < E3 && ox < E3) {
        if (oz0 < E3) {
            float* op = out + (((b * E3 + oz0) * E3 + oy) * E3 + ox) * 3;
#pragma unroll
            for (int o = 0; o < 3; ++o) op[o] = fmaxf(acc0[o], 0.f);
        }
        if (oz0 + 1 < E3) {
            float* op = out + (((b * E3 + oz0 + 1) * E3 + oy) * E3 + ox) * 3;
#pragma unroll
            for (int o = 0; o < 3; ++o) op[o] = fmaxf(acc1[o], 0.f);
        }
    }
}

extern "C" void kernel_launch(void* const* d_in, const int* in_sizes, int n_in,
                              void* d_out, int out_size, void* d_ws, size_t ws_size,
                              hipStream_t stream) {
    const int*   coords = (const int*)d_in[0];
    const float* voxels = (const float*)d_in[1];
    const float* W1     = (const float*)d_in[2];
    const float* W2     = (const float*)d_in[3];
    const float* W3     = (const float*)d_in[4];
    const float* b3     = (const float*)d_in[5];
    float* out = (float*)d_out;

    const int N = in_sizes[0] / 4;  // 100000

    // workspace: dense (50.3 MB) + x2 (78.1 MB) = 128.5 MB
    char* ws = (char*)d_ws;
    const size_t dense_elems = (size_t)2 * DGRID * DGRID * DGRID * 3;
    const size_t dense_bytes = dense_elems * sizeof(float);
    float* dense = (float*)ws;
    float* x2    = (float*)(ws + dense_bytes);

    const int n4 = (int)(dense_elems / 4);
    zero_k<<<(n4 + 255) / 256, 256, 0, stream>>>((float4*)dense, n4);

    scatter_k<<<(N * 3 + 255) / 256, 256, 0, stream>>>(coords, voxels, dense, N);

    const int nblk = 2 * 16 * 16 * 16;  // b x z-tiles x y-tiles x x-tiles (8^3 output tile)
    conv12_k<<<nblk, 256, 0, stream>>>(dense, W1, W2, x2);

    conv3_k<<<nblk, 256, 0, stream>>>(x2, W3, b3, out);
}

// Round 4
// 734.288 us; speedup vs baseline: 18.3608x; 18.3608x over previous
//
#include <hip/hip_runtime.h>

#define DGRID 128
#define E1 127
#define E2 125
#define E3 123
#define C1P 12            // x1 channels padded 9 -> 12 (48 B, 16B-aligned)

// ---------------- stage 0: zero dense grid ----------------
__global__ __launch_bounds__(256) void zero_k(float4* __restrict__ p, int n4) {
    int i = blockIdx.x * 256 + threadIdx.x;
    if (i < n4) p[i] = make_float4(0.f, 0.f, 0.f, 0.f);
}

// ---------------- stage 1: scatter voxels into dense grid ----------------
__global__ __launch_bounds__(256) void scatter_k(const int* __restrict__ coords,
                                                 const float* __restrict__ voxels,
                                                 float* __restrict__ dense, int N) {
    int i = blockIdx.x * blockDim.x + threadIdx.x;
    if (i >= N * 3) return;
    int n = i / 3, c = i - n * 3;
    int b = coords[n * 4 + 0];
    int z = coords[n * 4 + 1];
    int y = coords[n * 4 + 2];
    int x = coords[n * 4 + 3];
    int idx = (((b * DGRID + z) * DGRID + y) * DGRID + x) * 3 + c;
    atomicAdd(&dense[idx], voxels[n * 3 + c]);
}

// FMA 9 inputs (A.xyzw, Cc.xyzw, e0) x 5 outputs from LDS weight pointer WP
#define FMA9x5(ACC, WP)                                                          \
    do {                                                                         \
        _Pragma("unroll") for (int o = 0; o < 5; ++o)                            \
            ACC[o] += A.x * (WP)[0 * 5 + o] + A.y * (WP)[1 * 5 + o] +            \
                      A.z * (WP)[2 * 5 + o] + A.w * (WP)[3 * 5 + o] +            \
                      Cc.x * (WP)[4 * 5 + o] + Cc.y * (WP)[5 * 5 + o] +          \
                      Cc.z * (WP)[6 * 5 + o] + Cc.w * (WP)[7 * 5 + o] +          \
                      e0 * (WP)[8 * 5 + o];                                      \
    } while (0)

// ---------------- stage 2: fused conv1+conv2  dense -> x2 [B,125,125,125,5] ----------------
// Block: 256 threads, output tile 8x8x8 (2 z-outputs per thread).
// x1 tile 10x10x10 in LDS (channels padded to 12 -> ds_read_b128), conv1 reads dense from global.
__global__ __launch_bounds__(256, 2) void conv12_k(const float* __restrict__ dense,
                                                   const float* __restrict__ W1,
                                                   const float* __restrict__ W2,
                                                   float* __restrict__ x2) {
    __shared__ float sW1[216];
    __shared__ float sW2[1215];
    __shared__ __align__(16) float sX1[1000 * C1P];   // 48000 B

    const int tid = threadIdx.x;
    for (int i = tid; i < 216; i += 256) sW1[i] = W1[i];
    for (int i = tid; i < 1215; i += 256) sW2[i] = W2[i];

    int blk = blockIdx.x;
    const int txt = blk & 15; blk >>= 4;
    const int tyt = blk & 15; blk >>= 4;
    const int tzt = blk & 15; blk >>= 4;
    const int b = blk;
    const int z0 = tzt * 8, y0 = tyt * 8, x0 = txt * 8;

    __syncthreads();

    // ---- phase 1: compute x1 tile [10][10][10] in LDS from global dense
#pragma unroll 1
    for (int p = tid; p < 1000; p += 256) {
        const int xx = p % 10;
        const int xy = (p / 10) % 10;
        const int xz = p / 100;
        const int gz = z0 + xz, gy = y0 + xy, gx = x0 + xx;
        float acc[9];
#pragma unroll
        for (int o = 0; o < 9; ++o) acc[o] = 0.f;
#pragma unroll
        for (int kz = 0; kz < 2; ++kz) {
            const int dz = min(gz + kz, DGRID - 1);
#pragma unroll
            for (int ky = 0; ky < 2; ++ky) {
                const int dy = min(gy + ky, DGRID - 1);
#pragma unroll
                for (int kx = 0; kx < 2; ++kx) {
                    const int dx = min(gx + kx, DGRID - 1);
                    const float* dp = dense + (((b * DGRID + dz) * DGRID + dy) * DGRID + dx) * 3;
                    const float* wp = sW1 + ((kz * 2 + ky) * 2 + kx) * 27;
#pragma unroll
                    for (int ci = 0; ci < 3; ++ci) {
                        const float v = dp[ci];
#pragma unroll
                        for (int o = 0; o < 9; ++o) acc[o] += v * wp[ci * 9 + o];
                    }
                }
            }
        }
        float* op = sX1 + p * C1P;
#pragma unroll
        for (int o = 0; o < 9; ++o) op[o] = acc[o];
    }
    __syncthreads();

    // ---- phase 2: conv2 from LDS, 2 z-outputs per thread
    const int lx = tid & 7;
    const int ly = (tid >> 3) & 7;
    const int lz = tid >> 6;            // 0..3
    const int oy = y0 + ly, ox = x0 + lx;
    const int oz0 = z0 + 2 * lz;

    float acc0[5], acc1[5];
#pragma unroll
    for (int o = 0; o < 5; ++o) { acc0[o] = 0.f; acc1[o] = 0.f; }

#pragma unroll 1
    for (int r = 0; r < 4; ++r) {       // x1 z-row = 2*lz + r (uniform branches on r)
        const float* rowp = sX1 + ((2 * lz + r) * 100) * C1P;
        const float* wb0 = sW2 + (r * 9) * 45;          // kz = r     (for acc0, r<3)
        const float* wb1 = sW2 + ((r - 1) * 9) * 45;    // kz = r-1   (for acc1, r>0)
#pragma unroll
        for (int ky = 0; ky < 3; ++ky) {
#pragma unroll
            for (int kx = 0; kx < 3; ++kx) {
                const float* p = rowp + ((ly + ky) * 10 + (lx + kx)) * C1P;
                const float4 A  = *(const float4*)p;
                const float4 Cc = *(const float4*)(p + 4);
                const float  e0 = p[8];
                const int widx = (ky * 3 + kx) * 45;
                if (r < 3) { const float* wp = wb0 + widx; FMA9x5(acc0, wp); }
                if (r > 0) { const float* wp = wb1 + widx; FMA9x5(acc1, wp); }
            }
        }
    }

    if (oy < E2 && ox < E2) {
        if (oz0 < E2) {
            float* op = x2 + (((b * E2 + oz0) * E2 + oy) * E2 + ox) * 5;
#pragma unroll
            for (int o = 0; o < 5; ++o) op[o] = acc0[o];
        }
        if (oz0 + 1 < E2) {
            float* op = x2 + (((b * E2 + oz0 + 1) * E2 + oy) * E2 + ox) * 5;
#pragma unroll
            for (int o = 0; o < 5; ++o) op[o] = acc1[o];
        }
    }
}

// FMA 5 inputs x 3 outputs
#define FMA5x3(ACC, WP)                                                          \
    do {                                                                         \
        _Pragma("unroll") for (int o = 0; o < 3; ++o)                            \
            ACC[o] += v0 * (WP)[0 * 3 + o] + v1 * (WP)[1 * 3 + o] +              \
                      v2 * (WP)[2 * 3 + o] + v3 * (WP)[3 * 3 + o] +              \
                      v4 * (WP)[4 * 3 + o];                                      \
    } while (0)

// ---------------- stage 3: conv3 + bias + relu  [B,125,125,125,5] -> [B,123,123,123,3] ----------------
__global__ __launch_bounds__(256, 2) void conv3_k(const float* __restrict__ x2,
                                                  const float* __restrict__ W3,
                                                  const float* __restrict__ b3,
                                                  float* __restrict__ out) {
    __shared__ float w[405];
    for (int i = threadIdx.x; i < 405; i += 256) w[i] = W3[i];
    __syncthreads();

    int blk = blockIdx.x;
    const int txt = blk & 15; blk >>= 4;
    const int tyt = blk & 15; blk >>= 4;
    const int tzt = blk & 15; blk >>= 4;
    const int b = blk;
    const int z0 = tzt * 8, y0 = tyt * 8, x0 = txt * 8;

    const int tid = threadIdx.x;
    const int lx = tid & 7;
    const int ly = (tid >> 3) & 7;
    const int lz = tid >> 6;            // 0..3
    const int oy = y0 + ly, ox = x0 + lx;
    const int oz0 = z0 + 2 * lz;

    const float bb0 = b3[0], bb1 = b3[1], bb2 = b3[2];
    float acc0[3] = {bb0, bb1, bb2};
    float acc1[3] = {bb0, bb1, bb2};

#pragma unroll 1
    for (int r = 0; r < 4; ++r) {       // x2 z-row = oz0 + r (uniform branches on r)
        const int iz = min(oz0 + r, E2 - 1);
        const float* wb0 = w + (r * 9) * 15;
        const float* wb1 = w + ((r - 1) * 9) * 15;
#pragma unroll
        for (int ky = 0; ky < 3; ++ky) {
            const int iy = min(oy + ky, E2 - 1);
#pragma unroll
            for (int kx = 0; kx < 3; ++kx) {
                const int ix = min(ox + kx, E2 - 1);
                const float* p = x2 + (((b * E2 + iz) * E2 + iy) * E2 + ix) * 5;
                const float v0 = p[0], v1 = p[1], v2 = p[2], v3 = p[3], v4 = p[4];
                const int widx = (ky * 3 + kx) * 15;
                if (r < 3) { const float* wp = wb0 + widx; FMA5x3(acc0, wp); }
                if (r > 0) { const float* wp = wb1 + widx; FMA5x3(acc1, wp); }
            }
        }
    }

    if (oy < E3 && ox < E3) {
        if (oz0 < E3) {
            float* op = out + (((b * E3 + oz0) * E3 + oy) * E3 + ox) * 3;
#pragma unroll
            for (int o = 0; o < 3; ++o) op[o] = fmaxf(acc0[o], 0.f);
        }
        if (oz0 + 1 < E3) {
            float* op = out + (((b * E3 + oz0 + 1) * E3 + oy) * E3 + ox) * 3;
#pragma unroll
            for (int o = 0; o < 3; ++o) op[o] = fmaxf(acc1[o], 0.f);
        }
    }
}

extern "C" void kernel_launch(void* const* d_in, const int* in_sizes, int n_in,
                              void* d_out, int out_size, void* d_ws, size_t ws_size,
                              hipStream_t stream) {
    const int*   coords = (const int*)d_in[0];
    const float* voxels = (const float*)d_in[1];
    const float* W1     = (const float*)d_in[2];
    const float* W2     = (const float*)d_in[3];
    const float* W3     = (const float*)d_in[4];
    const float* b3     = (const float*)d_in[5];
    float* out = (float*)d_out;

    const int N = in_sizes[0] / 4;  // 100000

    // workspace: dense (50.3 MB) + x2 (78.1 MB) = 128.5 MB
    char* ws = (char*)d_ws;
    const size_t dense_elems = (size_t)2 * DGRID * DGRID * DGRID * 3;
    const size_t dense_bytes = dense_elems * sizeof(float);
    float* dense = (float*)ws;
    float* x2    = (float*)(ws + dense_bytes);

    const int n4 = (int)(dense_elems / 4);
    zero_k<<<(n4 + 255) / 256, 256, 0, stream>>>((float4*)dense, n4);

    scatter_k<<<(N * 3 + 255) / 256, 256, 0, stream>>>(coords, voxels, dense, N);

    const int nblk = 2 * 16 * 16 * 16;  // b x z-tiles x y-tiles x x-tiles (8^3 output tile)
    conv12_k<<<nblk, 256, 0, stream>>>(dense, W1, W2, x2);

    conv3_k<<<nblk, 256, 0, stream>>>(x2, W3, b3, out);
}

// Round 6
// 458.934 us; speedup vs baseline: 29.3770x; 1.6000x over previous
//
#include <hip/hip_runtime.h>
#include <hip/hip_bf16.h>

#define DGRID 128
#define E1 127
#define E2 125
#define E3 123

typedef __attribute__((ext_vector_type(8))) short short8;
typedef __attribute__((ext_vector_type(4))) float f32x4;

static __device__ __forceinline__ unsigned short f2bf(float f) {
    union { __hip_bfloat16 h; unsigned short u; } cv;
    cv.h = __float2bfloat16(f);
    return cv.u;
}

// swizzled byte offset within a y-row for position x (0..17, pad to 20 slots) and 16B-half h.
// row = 20 slots * 32B = 640B. XOR bits [4:6] by (x>>2): spreads consecutive-x 16B reads
// across all 8 bank-groups (2-way max => free per m136). Bijective within each 128B chunk.
static __device__ __forceinline__ int swz(int x, int h) {
    int off = x * 32 + h * 16;
    return off ^ (((x >> 2) & 7) << 4);
}

// ---------------- stage 0: zero dense grid ----------------
__global__ __launch_bounds__(256) void zero_k(float4* __restrict__ p, int n4) {
    int i = blockIdx.x * 256 + threadIdx.x;
    if (i < n4) p[i] = make_float4(0.f, 0.f, 0.f, 0.f);
}

// ---------------- stage 1: scatter voxels into dense grid ----------------
__global__ __launch_bounds__(256) void scatter_k(const int* __restrict__ coords,
                                                 const float* __restrict__ voxels,
                                                 float* __restrict__ dense, int N) {
    int i = blockIdx.x * blockDim.x + threadIdx.x;
    if (i >= N * 3) return;
    int n = i / 3, c = i - n * 3;
    int b = coords[n * 4 + 0];
    int z = coords[n * 4 + 1];
    int y = coords[n * 4 + 2];
    int x = coords[n * 4 + 3];
    int idx = (((b * DGRID + z) * DGRID + y) * DGRID + x) * 3 + c;
    atomicAdd(&dense[idx], voxels[n * 3 + c]);
}

// ---------------- stage 2: fused conv1 (fp32 VALU) + conv2 (bf16 MFMA) ----------------
// Block: 256 threads (4 waves). Output tile (z8, y8, x16) = 1024 positions of x2.
// Phase 1: x1 tile [10z][10y][18x] computed fp32, stored bf16 (9ch + 7 zero-pad = 16ch, 32B)
//          into swizzled LDS. Phase 2: implicit-GEMM, 14 x mfma_16x16x32_bf16 per 16 outputs;
//          weights live in 56 VGPRs (B-frags), loaded once.
__global__ __launch_bounds__(256, 2) void conv12_k(const float* __restrict__ dense,
                                                   const float* __restrict__ W1f,
                                                   const float* __restrict__ W2f,
                                                   float* __restrict__ x2) {
    __shared__ __align__(16) char sX1[64000];   // 10z * 10y * 640B rows

    const int tid = threadIdx.x;
    int blk = blockIdx.x;
    const int xt  = blk & 7;  blk >>= 3;
    const int tyt = blk & 15; blk >>= 4;
    const int tzt = blk & 15; blk >>= 4;
    const int b   = blk;
    const int z0 = tzt * 8, y0 = tyt * 8, x0 = xt * 16;

    // ---- phase 1: conv1, 4 positions per thread-rep, per-tap weights in regs (s_load'd)
#pragma unroll 1
    for (int rep = 0; rep < 2; ++rep) {
        const int pbase = rep * 1024 + tid * 4;
        if (pbase >= 1800) continue;
        int xs[4], ys[4], zs[4];
#pragma unroll
        for (int q = 0; q < 4; ++q) {
            int i = min(pbase + q, 1799);
            xs[q] = i % 18; int t2 = i / 18; ys[q] = t2 % 10; zs[q] = t2 / 10;
        }
        float acc[4][9];
#pragma unroll
        for (int q = 0; q < 4; ++q)
#pragma unroll
            for (int o = 0; o < 9; ++o) acc[q][o] = 0.f;

#pragma unroll 1
        for (int tap = 0; tap < 8; ++tap) {
            const int kz = tap >> 2, ky = (tap >> 1) & 1, kx = tap & 1;
            float w[27];                       // uniform global reads -> scalar loads
#pragma unroll
            for (int i = 0; i < 27; ++i) w[i] = W1f[tap * 27 + i];
#pragma unroll
            for (int q = 0; q < 4; ++q) {
                const int dz = min(z0 + zs[q] + kz, DGRID - 1);
                const int dy = min(y0 + ys[q] + ky, DGRID - 1);
                const int dx = min(x0 + xs[q] + kx, DGRID - 1);
                const float* dp = dense + (size_t)(((b * DGRID + dz) * DGRID + dy) * DGRID + dx) * 3;
                const float v0 = dp[0], v1 = dp[1], v2 = dp[2];
#pragma unroll
                for (int o = 0; o < 9; ++o)
                    acc[q][o] += v0 * w[o] + v1 * w[9 + o] + v2 * w[18 + o];
            }
        }
#pragma unroll
        for (int q = 0; q < 4; ++q) {
            if (pbase + q < 1800) {
                const int R = (zs[q] * 10 + ys[q]) * 640;
                short8 lo, hi;
#pragma unroll
                for (int o = 0; o < 8; ++o) lo[o] = (short)f2bf(acc[q][o]);
                hi[0] = (short)f2bf(acc[q][8]);
#pragma unroll
                for (int o = 1; o < 8; ++o) hi[o] = 0;
                *(short8*)(sX1 + R + swz(xs[q], 0)) = lo;
                *(short8*)(sX1 + R + swz(xs[q], 1)) = hi;
            }
        }
    }

    // ---- load conv2 B-fragments (weights) into registers, once.
    // B[k'][col], k' = tap*16+ci (tap 0..27 pad, ci 0..15 pad), col = out-ch (0..4 used).
    // lane mapping: col = lane&15, k' = 32t + (lane>>4)*8 + j
    const int lane = tid & 63;
    const int col  = lane & 15;
    const int q4   = lane >> 4;          // 0..3
    short8 B2[14];
#pragma unroll
    for (int t = 0; t < 14; ++t) {
#pragma unroll
        for (int j = 0; j < 8; ++j) {
            const int kp = t * 32 + q4 * 8 + j;
            const int tap = kp >> 4, ci = kp & 15;
            float v = 0.f;
            if (tap < 27 && ci < 9 && col < 5) v = W2f[(tap * 9 + ci) * 5 + col];
            B2[t][j] = (short)f2bf(v);
        }
    }
    __syncthreads();

    // ---- phase 2: conv2 via MFMA. Wave w handles groups g = w*16 + gi, g = (z'<<3)|y'.
    const int wv = tid >> 6;
    const int s  = q4 >> 1;              // tap-parity selector for A-read
    const int h  = q4 & 1;               // 16B-half (ci 0-7 vs 8-15)
#pragma unroll 1
    for (int gi = 0; gi < 16; ++gi) {
        const int g = wv * 16 + gi;
        const int zp = g >> 3, yp = g & 7;
        const int oz = z0 + zp, oy = y0 + yp;
        if (oz >= E2 || oy >= E2) continue;          // wave-uniform
        f32x4 acc = {0.f, 0.f, 0.f, 0.f};
#pragma unroll
        for (int t = 0; t < 14; ++t) {
            const int tap0 = 2 * t;
            const int tap1 = (2 * t + 1 > 26) ? 26 : 2 * t + 1;   // tap27: B==0, addr clamped
            const int kz0 = tap0 / 9, ky0 = (tap0 / 3) % 3, kx0 = tap0 % 3;
            const int kz1 = tap1 / 9, ky1 = (tap1 / 3) % 3, kx1 = tap1 % 3;
            const int r0 = ((zp + kz0) * 10 + (yp + ky0)) * 640;
            const int r1 = ((zp + kz1) * 10 + (yp + ky1)) * 640;
            const int xi = (lane & 15) + (s ? kx1 : kx0);
            const int off = (s ? r1 : r0) + swz(xi, h);
            const short8 a = *(const short8*)(sX1 + off);
            acc = __builtin_amdgcn_mfma_f32_16x16x32_bf16(a, B2[t], acc, 0, 0, 0);
        }
        // C: row = q4*4 + jj = x-offset, col = out-channel
        if (col < 5) {
#pragma unroll
            for (int jj = 0; jj < 4; ++jj) {
                const int ox = x0 + q4 * 4 + jj;
                if (ox < E2)
                    x2[(size_t)(((b * E2 + oz) * E2 + oy) * E2 + ox) * 5 + col] = acc[jj];
            }
        }
    }
}

// ---------------- stage 3: conv3 + bias + relu (fp32 VALU, taps-outer, reg weights) ----------------
// Block: 256 threads, output tile (z16, y8, x8), 4 z-outputs per thread. x2 read from global (L1).
__global__ __launch_bounds__(256, 4) void conv3_k(const float* __restrict__ x2,
                                                  const float* __restrict__ W3f,
                                                  const float* __restrict__ b3f,
                                                  float* __restrict__ out) {
    int blk = blockIdx.x;
    const int xt  = blk & 15; blk >>= 4;
    const int tyt = blk & 15; blk >>= 4;
    const int tzt = blk & 7;  blk >>= 3;
    const int b   = blk;
    const int z0 = tzt * 16, y0 = tyt * 8, x0 = xt * 8;

    const int tid = threadIdx.x;
    const int lx = tid & 7, ly = (tid >> 3) & 7, lzg = tid >> 6;
    const int oy = y0 + ly, ox = x0 + lx;
    const int ozb = z0 + lzg * 4;

    const float bb0 = b3f[0], bb1 = b3f[1], bb2 = b3f[2];
    float acc[4][3];
#pragma unroll
    for (int j = 0; j < 4; ++j) { acc[j][0] = bb0; acc[j][1] = bb1; acc[j][2] = bb2; }

#pragma unroll 1
    for (int tap = 0; tap < 27; ++tap) {
        const int kz = tap / 9, kr = tap % 9, ky = kr / 3, kx = kr % 3;
        float w[15];                           // uniform -> s_load
#pragma unroll
        for (int i = 0; i < 15; ++i) w[i] = W3f[tap * 15 + i];
        const int iy = min(oy + ky, E2 - 1);
        const int ix = min(ox + kx, E2 - 1);
#pragma unroll
        for (int j = 0; j < 4; ++j) {
            const int iz = min(ozb + j + kz, E2 - 1);
            const float* p = x2 + (size_t)(((b * E2 + iz) * E2 + iy) * E2 + ix) * 5;
            const float v0 = p[0], v1 = p[1], v2 = p[2], v3 = p[3], v4 = p[4];
#pragma unroll
            for (int o = 0; o < 3; ++o)
                acc[j][o] += v0 * w[o] + v1 * w[3 + o] + v2 * w[6 + o] +
                             v3 * w[9 + o] + v4 * w[12 + o];
        }
    }

    if (oy < E3 && ox < E3) {
#pragma unroll
        for (int j = 0; j < 4; ++j) {
            const int oz = ozb + j;
            if (oz < E3) {
                float* op = out + (size_t)(((b * E3 + oz) * E3 + oy) * E3 + ox) * 3;
#pragma unroll
                for (int o = 0; o < 3; ++o) op[o] = fmaxf(acc[j][o], 0.f);
            }
        }
    }
}

extern "C" void kernel_launch(void* const* d_in, const int* in_sizes, int n_in,
                              void* d_out, int out_size, void* d_ws, size_t ws_size,
                              hipStream_t stream) {
    const int*   coords = (const int*)d_in[0];
    const float* voxels = (const float*)d_in[1];
    const float* W1     = (const float*)d_in[2];
    const float* W2     = (const float*)d_in[3];
    const float* W3     = (const float*)d_in[4];
    const float* b3     = (const float*)d_in[5];
    float* out = (float*)d_out;

    const int N = in_sizes[0] / 4;  // 100000

    // workspace: dense (50.3 MB) + x2 (78.1 MB) = 128.5 MB
    char* ws = (char*)d_ws;
    const size_t dense_elems = (size_t)2 * DGRID * DGRID * DGRID * 3;
    const size_t dense_bytes = dense_elems * sizeof(float);
    float* dense = (float*)ws;
    float* x2    = (float*)(ws + dense_bytes);

    const int n4 = (int)(dense_elems / 4);
    zero_k<<<(n4 + 255) / 256, 256, 0, stream>>>((float4*)dense, n4);

    scatter_k<<<(N * 3 + 255) / 256, 256, 0, stream>>>(coords, voxels, dense, N);

    // conv12: blocks = B * z-tiles(16 of 8) * y-tiles(16 of 8) * x-tiles(8 of 16)
    const int nblk12 = 2 * 16 * 16 * 8;
    conv12_k<<<nblk12, 256, 0, stream>>>(dense, W1, W2, x2);

    // conv3: blocks = B * z-tiles(8 of 16) * y-tiles(16 of 8) * x-tiles(16 of 8)
    const int nblk3 = 2 * 8 * 16 * 16;
    conv3_k<<<nblk3, 256, 0, stream>>>(x2, W3, b3, out);
}

// Round 7
// 380.774 us; speedup vs baseline: 35.4071x; 1.2053x over previous
//
#include <hip/hip_runtime.h>
#include <hip/hip_bf16.h>

#define DGRID 128
#define E1 127
#define E2 125
#define E3 123

typedef __attribute__((ext_vector_type(8))) short short8;
typedef __attribute__((ext_vector_type(4))) float f32x4;

static __device__ __forceinline__ unsigned short f2bf(float f) {
    union { __hip_bfloat16 h; unsigned short u; } cv;
    cv.h = __float2bfloat16(f);
    return cv.u;
}

// conv12 x1-row swizzle: row = 20 slots * 32B = 640B, XOR bits[4:6] by (x>>2).
static __device__ __forceinline__ int swz(int x, int h) {
    int off = x * 32 + h * 16;
    return off ^ (((x >> 2) & 7) << 4);
}

// conv3 x2-record offset: row padded to 24 slots * 16B = 384B; XOR bits[4:6] by (row&7).
static __device__ __forceinline__ int r3off(int row, int x) {
    return row * 384 + ((x * 16) ^ ((row & 7) << 4));
}

// ---------------- stage 0: zero dense grid ----------------
__global__ __launch_bounds__(256) void zero_k(float4* __restrict__ p, int n4) {
    int i = blockIdx.x * 256 + threadIdx.x;
    if (i < n4) p[i] = make_float4(0.f, 0.f, 0.f, 0.f);
}

// ---------------- stage 1: scatter voxels into dense grid ----------------
__global__ __launch_bounds__(256) void scatter_k(const int* __restrict__ coords,
                                                 const float* __restrict__ voxels,
                                                 float* __restrict__ dense, int N) {
    int i = blockIdx.x * blockDim.x + threadIdx.x;
    if (i >= N * 3) return;
    int n = i / 3, c = i - n * 3;
    int b = coords[n * 4 + 0];
    int z = coords[n * 4 + 1];
    int y = coords[n * 4 + 2];
    int x = coords[n * 4 + 3];
    int idx = (((b * DGRID + z) * DGRID + y) * DGRID + x) * 3 + c;
    atomicAdd(&dense[idx], voxels[n * 3 + c]);
}

// ---------------- stage 2: fused conv1 (fp32 VALU) + conv2 (bf16 MFMA) ----------------
// Block: 256 threads (4 waves). Output tile (z4, y8, x16) of x2.
// Phase 1: x1 tile [6z][10y][18x] fp32 -> bf16 (9ch+7 pad) into swizzled LDS (38.4 KB).
// Phase 2: implicit GEMM, 14 x mfma_16x16x32_bf16 per 16 outputs; weights in 56 VGPRs.
__global__ __launch_bounds__(256, 4) void conv12_k(const float* __restrict__ dense,
                                                   const float* __restrict__ W1f,
                                                   const float* __restrict__ W2f,
                                                   float* __restrict__ x2) {
    __shared__ __align__(16) char sX1[38400];   // 6z * 10y rows * 640B

    const int tid = threadIdx.x;
    int blk = blockIdx.x;
    const int xt  = blk & 7;  blk >>= 3;
    const int tyt = blk & 15; blk >>= 4;
    const int tzt = blk & 31; blk >>= 5;
    const int b   = blk;
    const int z0 = tzt * 4, y0 = tyt * 8, x0 = xt * 16;

    // ---- phase 1: conv1, 4 positions per thread-rep, per-tap weights s_load'd
#pragma unroll 1
    for (int rep = 0; rep < 2; ++rep) {
        const int pbase = rep * 1024 + tid * 4;
        if (pbase >= 1080) continue;
        int xs[4], ys[4], zs[4];
#pragma unroll
        for (int q = 0; q < 4; ++q) {
            int i = min(pbase + q, 1079);
            xs[q] = i % 18; int t2 = i / 18; ys[q] = t2 % 10; zs[q] = t2 / 10;
        }
        float acc[4][9];
#pragma unroll
        for (int q = 0; q < 4; ++q)
#pragma unroll
            for (int o = 0; o < 9; ++o) acc[q][o] = 0.f;

#pragma unroll 1
        for (int tap = 0; tap < 8; ++tap) {
            const int kz = tap >> 2, ky = (tap >> 1) & 1, kx = tap & 1;
            float w[27];                       // uniform -> scalar loads
#pragma unroll
            for (int i = 0; i < 27; ++i) w[i] = W1f[tap * 27 + i];
#pragma unroll
            for (int q = 0; q < 4; ++q) {
                const int dz = min(z0 + zs[q] + kz, DGRID - 1);
                const int dy = min(y0 + ys[q] + ky, DGRID - 1);
                const int dx = min(x0 + xs[q] + kx, DGRID - 1);
                const float* dp = dense + (size_t)(((b * DGRID + dz) * DGRID + dy) * DGRID + dx) * 3;
                const float v0 = dp[0], v1 = dp[1], v2 = dp[2];
#pragma unroll
                for (int o = 0; o < 9; ++o)
                    acc[q][o] += v0 * w[o] + v1 * w[9 + o] + v2 * w[18 + o];
            }
        }
#pragma unroll
        for (int q = 0; q < 4; ++q) {
            if (pbase + q < 1080) {
                const int R = (zs[q] * 10 + ys[q]) * 640;
                short8 lo, hi;
#pragma unroll
                for (int o = 0; o < 8; ++o) lo[o] = (short)f2bf(acc[q][o]);
                hi[0] = (short)f2bf(acc[q][8]);
#pragma unroll
                for (int o = 1; o < 8; ++o) hi[o] = 0;
                *(short8*)(sX1 + R + swz(xs[q], 0)) = lo;
                *(short8*)(sX1 + R + swz(xs[q], 1)) = hi;
            }
        }
    }

    // ---- conv2 B-fragments: k' = tap*16+ci, col = out-ch; lane: col=lane&15, k'=32t+(lane>>4)*8+j
    const int lane = tid & 63;
    const int col  = lane & 15;
    const int q4   = lane >> 4;          // 0..3
    short8 B2[14];
#pragma unroll
    for (int t = 0; t < 14; ++t) {
#pragma unroll
        for (int j = 0; j < 8; ++j) {
            const int kp = t * 32 + q4 * 8 + j;
            const int tap = kp >> 4, ci = kp & 15;
            float v = 0.f;
            if (tap < 27 && ci < 9 && col < 5) v = W2f[(tap * 9 + ci) * 5 + col];
            B2[t][j] = (short)f2bf(v);
        }
    }
    __syncthreads();

    // ---- phase 2: conv2 via MFMA. Groups g = (z'<<3)|y', 32 groups / 4 waves.
    const int wv = tid >> 6;
    const int s  = q4 >> 1;              // tap-parity selector
    const int h  = q4 & 1;               // 16B-half (ci 0-7 / 8-15)
#pragma unroll 1
    for (int gi = 0; gi < 8; ++gi) {
        const int g = wv * 8 + gi;
        const int zp = g >> 3, yp = g & 7;
        const int oz = z0 + zp, oy = y0 + yp;
        if (oz >= E2 || oy >= E2) continue;          // wave-uniform
        f32x4 acc = {0.f, 0.f, 0.f, 0.f};
#pragma unroll
        for (int t = 0; t < 14; ++t) {
            const int tap0 = 2 * t;
            const int tap1 = (2 * t + 1 > 26) ? 26 : 2 * t + 1;   // tap27: B==0
            const int kz0 = tap0 / 9, ky0 = (tap0 / 3) % 3, kx0 = tap0 % 3;
            const int kz1 = tap1 / 9, ky1 = (tap1 / 3) % 3, kx1 = tap1 % 3;
            const int r0 = ((zp + kz0) * 10 + (yp + ky0)) * 640;
            const int r1 = ((zp + kz1) * 10 + (yp + ky1)) * 640;
            const int xi = (lane & 15) + (s ? kx1 : kx0);
            const int off = (s ? r1 : r0) + swz(xi, h);
            const short8 a = *(const short8*)(sX1 + off);
            acc = __builtin_amdgcn_mfma_f32_16x16x32_bf16(a, B2[t], acc, 0, 0, 0);
        }
        if (col < 5) {
#pragma unroll
            for (int jj = 0; jj < 4; ++jj) {
                const int ox = x0 + q4 * 4 + jj;
                if (ox < E2)
                    x2[(size_t)(((b * E2 + oz) * E2 + oy) * E2 + ox) * 5 + col] = acc[jj];
            }
        }
    }
}

// ---------------- stage 3: conv3 + bias + relu via MFMA ----------------
// Block: 256 threads (4 waves). Output tile (z8, y8, x16). x2 halo 10x10x18 staged in LDS
// as bf16 8-ch records (16B), row-XOR swizzled (38.4 KB). 7 x mfma per 16 outputs;
// A-frag = one ds_read_b128 (k' = tap*8 + ci).
__global__ __launch_bounds__(256, 4) void conv3_k(const float* __restrict__ x2,
                                                  const float* __restrict__ W3f,
                                                  const float* __restrict__ b3f,
                                                  float* __restrict__ out) {
    __shared__ __align__(16) char sX2[38400];   // 100 rows * 384B

    const int tid = threadIdx.x;
    int blk = blockIdx.x;
    const int xt  = blk & 7;  blk >>= 3;
    const int tyt = blk & 15; blk >>= 4;
    const int tzt = blk & 15; blk >>= 4;
    const int b   = blk;
    const int z0 = tzt * 8, y0 = tyt * 8, x0 = xt * 16;

    // ---- stage x2 halo tile: 10z * 10y * 18x positions
#pragma unroll 1
    for (int p = tid; p < 1800; p += 256) {
        const int xp = p % 18; int t2 = p / 18;
        const int yp = t2 % 10; const int zp = t2 / 10;
        const int iz = min(z0 + zp, E2 - 1);
        const int iy = min(y0 + yp, E2 - 1);
        const int ix = min(x0 + xp, E2 - 1);
        const float* sp = x2 + (size_t)(((b * E2 + iz) * E2 + iy) * E2 + ix) * 5;
        short8 rec;
        rec[0] = (short)f2bf(sp[0]); rec[1] = (short)f2bf(sp[1]);
        rec[2] = (short)f2bf(sp[2]); rec[3] = (short)f2bf(sp[3]);
        rec[4] = (short)f2bf(sp[4]);
        rec[5] = 0; rec[6] = 0; rec[7] = 0;
        *(short8*)(sX2 + r3off(zp * 10 + yp, xp)) = rec;
    }

    // ---- conv3 B-fragments: k' = tap*8+ci (27 taps + 1 pad), col = out-ch (3 used)
    const int lane = tid & 63;
    const int col  = lane & 15;
    const int q4   = lane >> 4;
    short8 B3[7];
#pragma unroll
    for (int t = 0; t < 7; ++t) {
        const int tap = 4 * t + q4;          // k' = 32t + q4*8 + j -> tap = 4t+q4, ci = j
#pragma unroll
        for (int j = 0; j < 8; ++j) {
            float v = 0.f;
            if (tap < 27 && j < 5 && col < 3) v = W3f[(tap * 5 + j) * 3 + col];
            B3[t][j] = (short)f2bf(v);
        }
    }
    const float bias = (col < 3) ? b3f[col] : 0.f;
    __syncthreads();

    // ---- MFMA: groups g = (z'<<3)|y', 64 groups / 4 waves = 16 per wave
    const int wv = tid >> 6;
#pragma unroll 1
    for (int gi = 0; gi < 16; ++gi) {
        const int g = wv * 16 + gi;
        const int zp = g >> 3, yp = g & 7;
        const int oz = z0 + zp, oy = y0 + yp;
        if (oz >= E3 || oy >= E3) continue;          // wave-uniform
        f32x4 acc = {0.f, 0.f, 0.f, 0.f};
#pragma unroll
        for (int t = 0; t < 7; ++t) {
            const int tap = (4 * t + q4 > 26) ? 26 : 4 * t + q4;   // tap27: B==0
            const int kz = tap / 9, ky = (tap / 3) % 3, kx = tap % 3;
            const int row = (zp + kz) * 10 + (yp + ky);
            const int xi = (lane & 15) + kx;
            const short8 a = *(const short8*)(sX2 + r3off(row, xi));
            acc = __builtin_amdgcn_mfma_f32_16x16x32_bf16(a, B3[t], acc, 0, 0, 0);
        }
        if (col < 3) {
#pragma unroll
            for (int jj = 0; jj < 4; ++jj) {
                const int ox = x0 + q4 * 4 + jj;
                if (ox < E3)
                    out[(size_t)(((b * E3 + oz) * E3 + oy) * E3 + ox) * 3 + col] =
                        fmaxf(acc[jj] + bias, 0.f);
            }
        }
    }
}

extern "C" void kernel_launch(void* const* d_in, const int* in_sizes, int n_in,
                              void* d_out, int out_size, void* d_ws, size_t ws_size,
                              hipStream_t stream) {
    const int*   coords = (const int*)d_in[0];
    const float* voxels = (const float*)d_in[1];
    const float* W1     = (const float*)d_in[2];
    const float* W2     = (const float*)d_in[3];
    const float* W3     = (const float*)d_in[4];
    const float* b3     = (const float*)d_in[5];
    float* out = (float*)d_out;

    const int N = in_sizes[0] / 4;  // 100000

    // workspace: dense (50.3 MB) + x2 (78.1 MB) = 128.5 MB
    char* ws = (char*)d_ws;
    const size_t dense_elems = (size_t)2 * DGRID * DGRID * DGRID * 3;
    const size_t dense_bytes = dense_elems * sizeof(float);
    float* dense = (float*)ws;
    float* x2    = (float*)(ws + dense_bytes);

    const int n4 = (int)(dense_elems / 4);
    zero_k<<<(n4 + 255) / 256, 256, 0, stream>>>((float4*)dense, n4);

    scatter_k<<<(N * 3 + 255) / 256, 256, 0, stream>>>(coords, voxels, dense, N);

    // conv12: B * z-tiles(32 of 4) * y-tiles(16 of 8) * x-tiles(8 of 16)
    const int nblk12 = 2 * 32 * 16 * 8;
    conv12_k<<<nblk12, 256, 0, stream>>>(dense, W1, W2, x2);

    // conv3: B * z-tiles(16 of 8) * y-tiles(16 of 8) * x-tiles(8 of 16)
    const int nblk3 = 2 * 16 * 16 * 8;
    conv3_k<<<nblk3, 256, 0, stream>>>(x2, W3, b3, out);
}